// Round 3
// baseline (674.821 us; speedup 1.0000x reference)
//
#include <hip/hip_runtime.h>

// 2-layer GCN: h1 = emb[x] @ W1; agg+b1+relu; @ W2; agg+b2.
// CSR built per-launch via two-level binned counting sort (no global atomics).
// Aggregation is edge-parallel per 128-node bin with LDS fp32-atomic
// accumulators (R2 showed per-node serial edge loops are latency-bound:
// VALUBusy 18%, 0.89 TB/s on an 87MB gather).

#define BS   256
#define NBLK 256          // blocks for hist/binscatter passes
#define BINSHIFT 7        // 128 nodes per bin
#define BIN  128
#define MAXBINS 1024

// ---- pass A: per-block histograms of dst bins -------------------------------
__global__ void k_hist(const int* __restrict__ dst, int E, int NBINS,
                       int* __restrict__ histG) {
    __shared__ int h[MAXBINS];
    int t = threadIdx.x;
    for (int i = t; i < NBINS; i += BS) h[i] = 0;
    __syncthreads();
    int chunk = (E + NBLK - 1) / NBLK;
    int s = blockIdx.x * chunk;
    int eend = s + chunk; if (eend > E) eend = E;
    for (int e = s + t; e < eend; e += BS) atomicAdd(&h[dst[e] >> BINSHIFT], 1);
    __syncthreads();
    for (int i = t; i < NBINS; i += BS) histG[i * NBLK + blockIdx.x] = h[i];
}

// ---- hierarchical exclusive scan over L = NBINS*NBLK ints -------------------
__global__ void k_scanA(const int* __restrict__ in, int L,
                        int* __restrict__ partial, int* __restrict__ bsum) {
    __shared__ int s[BS];
    int t = threadIdx.x;
    int i = blockIdx.x * BS + t;
    int v = (i < L) ? in[i] : 0;
    s[t] = v;
    __syncthreads();
    for (int off = 1; off < BS; off <<= 1) {
        int add = (t >= off) ? s[t - off] : 0;
        __syncthreads();
        s[t] += add;
        __syncthreads();
    }
    if (i < L) partial[i] = s[t] - v;
    if (t == BS - 1) bsum[blockIdx.x] = s[BS - 1];
}

__global__ void k_scanB(const int* __restrict__ bsum, int nB, int* __restrict__ boff) {
    __shared__ int s[BS];
    int t = threadIdx.x;
    int PER = (nB + BS - 1) / BS;
    int loc[8];
    int base = t * PER;
    int sum = 0;
    for (int j = 0; j < PER && j < 8; j++) {
        int idx = base + j;
        int v = (idx < nB) ? bsum[idx] : 0;
        loc[j] = sum;
        sum += v;
    }
    s[t] = sum;
    __syncthreads();
    for (int off = 1; off < BS; off <<= 1) {
        int add = (t >= off) ? s[t - off] : 0;
        __syncthreads();
        s[t] += add;
        __syncthreads();
    }
    int ex = s[t] - sum;
    for (int j = 0; j < PER && j < 8; j++) {
        int idx = base + j;
        if (idx < nB) boff[idx] = ex + loc[j];
    }
}

__global__ void k_scanC(const int* __restrict__ partial, const int* __restrict__ boff,
                        int L, int* __restrict__ outArr) {
    int i = blockIdx.x * BS + threadIdx.x;
    if (i < L) outArr[i] = partial[i] + boff[i >> 8];
}

// ---- pass C: scatter edges into bin-partitioned order (LDS cursors only) ----
__global__ void k_binscatter(const int* __restrict__ src, const int* __restrict__ dst,
                             int E, int NBINS, const int* __restrict__ scanArr,
                             int2* __restrict__ pairs) {
    __shared__ int cur[MAXBINS];
    int t = threadIdx.x;
    for (int i = t; i < NBINS; i += BS) cur[i] = scanArr[i * NBLK + blockIdx.x];
    __syncthreads();
    int chunk = (E + NBLK - 1) / NBLK;
    int s = blockIdx.x * chunk;
    int eend = s + chunk; if (eend > E) eend = E;
    for (int e = s + t; e < eend; e += BS) {
        int d = dst[e];
        int pos = atomicAdd(&cur[d >> BINSHIFT], 1);     // LDS atomic
        pairs[pos] = make_int2(src[e], d);
    }
}

// ---- pass D: per-bin counting sort -> CSR col + local-dst bytes + dinv ------
__global__ void k_binsort(const int2* __restrict__ pairs, const int* __restrict__ scanArr,
                          int NBINS, int N, int E,
                          int* __restrict__ row_start, float* __restrict__ dinv,
                          int* __restrict__ col, unsigned char* __restrict__ dstl) {
    __shared__ int ldeg[BIN];
    __shared__ int lrs[BIN];
    __shared__ int cur[BIN];
    int b = blockIdx.x;
    int t = threadIdx.x;
    int node0 = b << BINSHIFT;
    int e0 = scanArr[b * NBLK];
    int e1 = (b + 1 < NBINS) ? scanArr[(b + 1) * NBLK] : E;
    if (t < BIN) ldeg[t] = 0;
    __syncthreads();
    for (int e = e0 + t; e < e1; e += BS)
        atomicAdd(&ldeg[pairs[e].y - node0], 1);
    __syncthreads();
    if (t < BIN) lrs[t] = ldeg[t];
    __syncthreads();
    for (int off = 1; off < BIN; off <<= 1) {
        int add = (t < BIN && t >= off) ? lrs[t - off] : 0;
        __syncthreads();
        if (t < BIN) lrs[t] += add;
        __syncthreads();
    }
    if (t < BIN) {
        int ex = lrs[t] - ldeg[t];
        cur[t] = ex;
        int n = node0 + t;
        if (n < N) {
            row_start[n] = e0 + ex;
            dinv[n] = rsqrtf((float)(ldeg[t] + 1));
        }
    }
    __syncthreads();
    for (int e = e0 + t; e < e1; e += BS) {
        int2 p = pairs[e];
        int dl = p.y - node0;
        int pos = atomicAdd(&cur[dl], 1);                // LDS atomic
        col[e0 + pos] = p.x;
        dstl[e0 + pos] = (unsigned char)dl;
    }
}

// ---- h1[n][c] = sum_k emb[x[n]][k] * W1[k][c]   (N x 16 @ 16 x 32) ----------
__global__ void k_mm1(const int* __restrict__ x, const float* __restrict__ emb,
                      const float* __restrict__ W1, int N, float* __restrict__ h1) {
    __shared__ float sW[16 * 32];
    __shared__ float sE[8][17];
    int t = threadIdx.x;
    sW[t] = W1[t];
    sW[t + 256] = W1[t + 256];
    int n0 = blockIdx.x * 8;
    if (t < 128) {
        int nl = t >> 4, k = t & 15;
        int n = n0 + nl;
        sE[nl][k] = (n < N) ? emb[x[n] * 16 + k] : 0.f;
    }
    __syncthreads();
    int nl = t >> 5, c = t & 31;
    int n = n0 + nl;
    if (n < N) {
        float acc = 0.f;
        #pragma unroll
        for (int k = 0; k < 16; k++) acc += sE[nl][k] * sW[k * 32 + c];
        h1[n * 32 + c] = acc;
    }
}

// ---- fused layer-1 aggregate + b1 + relu + GEMM W2 -> h2 --------------------
// one block per 128-node bin; edge-parallel: 32 edges x 8 float4-channel-groups
__global__ __launch_bounds__(BS) void k_agg1mm2(
    const float* __restrict__ h1, const int* __restrict__ row_start,
    const float* __restrict__ dinv, const int* __restrict__ col,
    const unsigned char* __restrict__ dstl, const float* __restrict__ b1,
    const float* __restrict__ W2, int N, int E, float* __restrict__ h2) {
    __shared__ float acc[BIN][33];              // pad 33: break c<->bank alignment
    __shared__ float sW[32 * 16];
    int t = threadIdx.x;
    int node0 = blockIdx.x << BINSHIFT;
    sW[t] = W2[t];
    sW[t + 256] = W2[t + 256];
    for (int i = t; i < BIN * 33; i += BS) ((float*)acc)[i] = 0.f;
    __syncthreads();
    int nend = node0 + BIN;
    int e0 = row_start[node0];
    int e1 = (nend < N) ? row_start[nend] : E;
    int es = t >> 3, cg = t & 7;
    for (int e = e0 + es; e < e1; e += 32) {
        int s = col[e];                          // 8 lanes broadcast
        int dl = dstl[e];
        float ds = dinv[s];
        float4 v = *(const float4*)(h1 + s * 32 + cg * 4);  // 8 lanes = 1 line
        atomicAdd(&acc[dl][cg * 4 + 0], ds * v.x);
        atomicAdd(&acc[dl][cg * 4 + 1], ds * v.y);
        atomicAdd(&acc[dl][cg * 4 + 2], ds * v.z);
        atomicAdd(&acc[dl][cg * 4 + 3], ds * v.w);
    }
    __syncthreads();
    // self-loop + norm + bias + relu, in place
    {
        int c = t & 31;
        float bc = b1[c];
        for (int i = t >> 5; i < BIN; i += 8) {
            int n = node0 + i;
            if (n < N) {
                float di = dinv[n];
                float v = acc[i][c] + di * h1[n * 32 + c];
                acc[i][c] = fmaxf(v * di + bc, 0.f);
            }
        }
    }
    __syncthreads();
    // mm2: 128 nodes x 16 out-channels
    {
        int co = t & 15;
        for (int i = t >> 4; i < BIN; i += 16) {
            int n = node0 + i;
            if (n < N) {
                float a = 0.f;
                #pragma unroll
                for (int k = 0; k < 32; k++) a += acc[i][k] * sW[k * 16 + co];
                h2[n * 16 + co] = a;
            }
        }
    }
}

// ---- layer-2 aggregate + b2 -> out ------------------------------------------
// one block per bin; edge-parallel: 64 edges x 4 float4-channel-groups
__global__ __launch_bounds__(BS) void k_agg2(
    const float* __restrict__ h2, const int* __restrict__ row_start,
    const float* __restrict__ dinv, const int* __restrict__ col,
    const unsigned char* __restrict__ dstl, const float* __restrict__ b2,
    int N, int E, float* __restrict__ out) {
    __shared__ float acc[BIN][17];
    int t = threadIdx.x;
    int node0 = blockIdx.x << BINSHIFT;
    for (int i = t; i < BIN * 17; i += BS) ((float*)acc)[i] = 0.f;
    __syncthreads();
    int nend = node0 + BIN;
    int e0 = row_start[node0];
    int e1 = (nend < N) ? row_start[nend] : E;
    int es = t >> 2, cg = t & 3;
    for (int e = e0 + es; e < e1; e += 64) {
        int s = col[e];
        int dl = dstl[e];
        float ds = dinv[s];
        float4 v = *(const float4*)(h2 + s * 16 + cg * 4);
        atomicAdd(&acc[dl][cg * 4 + 0], ds * v.x);
        atomicAdd(&acc[dl][cg * 4 + 1], ds * v.y);
        atomicAdd(&acc[dl][cg * 4 + 2], ds * v.z);
        atomicAdd(&acc[dl][cg * 4 + 3], ds * v.w);
    }
    __syncthreads();
    int c = t & 15;
    float bc = b2[c];
    for (int i = t >> 4; i < BIN; i += 16) {
        int n = node0 + i;
        if (n < N) {
            float di = dinv[n];
            float v = acc[i][c] + di * h2[n * 16 + c];
            out[n * 16 + c] = v * di + bc;
        }
    }
}

extern "C" void kernel_launch(void* const* d_in, const int* in_sizes, int n_in,
                              void* d_out, int out_size, void* d_ws, size_t ws_size,
                              hipStream_t stream) {
    const int*   x   = (const int*)d_in[0];
    const int*   ei  = (const int*)d_in[1];
    const float* emb = (const float*)d_in[2];
    const float* W1  = (const float*)d_in[3];
    const float* b1  = (const float*)d_in[4];
    const float* W2  = (const float*)d_in[5];
    const float* b2  = (const float*)d_in[6];
    float* out = (float*)d_out;

    const int N = in_sizes[0];
    const int E = in_sizes[1] / 2;
    const int* srcp = ei;
    const int* dstp = ei + E;
    const int NBINS = (N + BIN - 1) >> BINSHIFT;   // 782 for N=100000
    const int L = NBINS * NBLK;
    const int nB2 = (L + BS - 1) / BS;

    char* w = (char*)d_ws;
    auto carve = [&](size_t bytes) {
        void* p = (void*)w;
        w += (bytes + 255) & ~size_t(255);
        return p;
    };
    int*   histG     = (int*)carve((size_t)L * 4);
    int*   partial   = (int*)carve((size_t)L * 4);
    int*   bsum      = (int*)carve((size_t)nB2 * 4);
    int*   boff      = (int*)carve((size_t)nB2 * 4);
    int*   scanArr   = (int*)carve((size_t)L * 4);
    int*   row_start = (int*)carve((size_t)N * 4);
    float* dinv      = (float*)carve((size_t)N * 4);
    int*   col       = (int*)carve((size_t)E * 4);
    unsigned char* dstl = (unsigned char*)carve((size_t)E);
    // pairs (int2, E*8) and h1 (N*32*4) have disjoint lifetimes -> share
    size_t pairsB = (size_t)E * 8, h1B = (size_t)N * 32 * 4;
    void*  shared12  = carve(pairsB > h1B ? pairsB : h1B);
    int2*  pairs     = (int2*)shared12;
    float* h1        = (float*)shared12;
    float* h2        = (float*)carve((size_t)N * 16 * 4);
    (void)ws_size; (void)n_in; (void)out_size;

    int gL = (L + BS - 1) / BS;
    k_hist<<<NBLK, BS, 0, stream>>>(dstp, E, NBINS, histG);
    k_scanA<<<gL, BS, 0, stream>>>(histG, L, partial, bsum);
    k_scanB<<<1, BS, 0, stream>>>(bsum, nB2, boff);
    k_scanC<<<gL, BS, 0, stream>>>(partial, boff, L, scanArr);
    k_binscatter<<<NBLK, BS, 0, stream>>>(srcp, dstp, E, NBINS, scanArr, pairs);
    k_binsort<<<NBINS, BS, 0, stream>>>(pairs, scanArr, NBINS, N, E,
                                        row_start, dinv, col, dstl);

    int g8 = (N + 7) / 8;
    k_mm1<<<g8, BS, 0, stream>>>(x, emb, W1, N, h1);
    k_agg1mm2<<<NBINS, BS, 0, stream>>>(h1, row_start, dinv, col, dstl, b1, W2,
                                        N, E, h2);
    k_agg2<<<NBINS, BS, 0, stream>>>(h2, row_start, dinv, col, dstl, b2,
                                     N, E, out);
}

// Round 4
// 273.296 us; speedup vs baseline: 2.4692x; 2.4692x over previous
//
#include <hip/hip_runtime.h>

// 2-layer GCN: h1 = emb[x] @ W1; agg+b1+relu; @ W2; agg+b2.
// CSR built per-launch via two-level binned counting sort (no global atomics).
// Aggregation: node-per-wave gather with 4-8 independent lines in flight
// (R2 was latency-bound at 2 lines/wave; R3's LDS-atomic edge-parallel
// variant regressed 3.6x -- 32 ds_add RMWs/edge serialize the LDS pipe).

#define BS   256
#define NBLK 256          // blocks for hist/binscatter passes
#define BINSHIFT 7        // 128 nodes per bin
#define BIN  128
#define MAXBINS 1024

// ---- pass A: per-block histograms of dst bins -------------------------------
__global__ void k_hist(const int* __restrict__ dst, int E, int NBINS,
                       int* __restrict__ histG) {
    __shared__ int h[MAXBINS];
    int t = threadIdx.x;
    for (int i = t; i < NBINS; i += BS) h[i] = 0;
    __syncthreads();
    int chunk = (E + NBLK - 1) / NBLK;
    int s = blockIdx.x * chunk;
    int eend = s + chunk; if (eend > E) eend = E;
    for (int e = s + t; e < eend; e += BS) atomicAdd(&h[dst[e] >> BINSHIFT], 1);
    __syncthreads();
    for (int i = t; i < NBINS; i += BS) histG[i * NBLK + blockIdx.x] = h[i];
}

// ---- hierarchical exclusive scan over L = NBINS*NBLK ints -------------------
__global__ void k_scanA(const int* __restrict__ in, int L,
                        int* __restrict__ partial, int* __restrict__ bsum) {
    __shared__ int s[BS];
    int t = threadIdx.x;
    int i = blockIdx.x * BS + t;
    int v = (i < L) ? in[i] : 0;
    s[t] = v;
    __syncthreads();
    for (int off = 1; off < BS; off <<= 1) {
        int add = (t >= off) ? s[t - off] : 0;
        __syncthreads();
        s[t] += add;
        __syncthreads();
    }
    if (i < L) partial[i] = s[t] - v;
    if (t == BS - 1) bsum[blockIdx.x] = s[BS - 1];
}

__global__ void k_scanB(const int* __restrict__ bsum, int nB, int* __restrict__ boff) {
    __shared__ int s[BS];
    int t = threadIdx.x;
    int PER = (nB + BS - 1) / BS;
    int loc[8];
    int base = t * PER;
    int sum = 0;
    for (int j = 0; j < PER && j < 8; j++) {
        int idx = base + j;
        int v = (idx < nB) ? bsum[idx] : 0;
        loc[j] = sum;
        sum += v;
    }
    s[t] = sum;
    __syncthreads();
    for (int off = 1; off < BS; off <<= 1) {
        int add = (t >= off) ? s[t - off] : 0;
        __syncthreads();
        s[t] += add;
        __syncthreads();
    }
    int ex = s[t] - sum;
    for (int j = 0; j < PER && j < 8; j++) {
        int idx = base + j;
        if (idx < nB) boff[idx] = ex + loc[j];
    }
}

__global__ void k_scanC(const int* __restrict__ partial, const int* __restrict__ boff,
                        int L, int* __restrict__ outArr) {
    int i = blockIdx.x * BS + threadIdx.x;
    if (i < L) outArr[i] = partial[i] + boff[i >> 8];
}

// ---- pass C: scatter edges into bin-partitioned order (LDS cursors only) ----
__global__ void k_binscatter(const int* __restrict__ src, const int* __restrict__ dst,
                             int E, int NBINS, const int* __restrict__ scanArr,
                             int2* __restrict__ pairs) {
    __shared__ int cur[MAXBINS];
    int t = threadIdx.x;
    for (int i = t; i < NBINS; i += BS) cur[i] = scanArr[i * NBLK + blockIdx.x];
    __syncthreads();
    int chunk = (E + NBLK - 1) / NBLK;
    int s = blockIdx.x * chunk;
    int eend = s + chunk; if (eend > E) eend = E;
    for (int e = s + t; e < eend; e += BS) {
        int d = dst[e];
        int pos = atomicAdd(&cur[d >> BINSHIFT], 1);     // LDS atomic
        pairs[pos] = make_int2(src[e], d);
    }
}

// ---- pass D: per-bin counting sort -> final CSR + deg/row_start/dinv --------
__global__ void k_binsort(const int2* __restrict__ pairs, const int* __restrict__ scanArr,
                          int NBINS, int N, int E,
                          int* __restrict__ row_start, int* __restrict__ deg,
                          float* __restrict__ dinv, int* __restrict__ col) {
    __shared__ int ldeg[BIN];
    __shared__ int lrs[BIN];
    __shared__ int cur[BIN];
    int b = blockIdx.x;
    int t = threadIdx.x;
    int node0 = b << BINSHIFT;
    int e0 = scanArr[b * NBLK];
    int e1 = (b + 1 < NBINS) ? scanArr[(b + 1) * NBLK] : E;
    if (t < BIN) ldeg[t] = 0;
    __syncthreads();
    for (int e = e0 + t; e < e1; e += BS)
        atomicAdd(&ldeg[pairs[e].y - node0], 1);
    __syncthreads();
    if (t < BIN) lrs[t] = ldeg[t];
    __syncthreads();
    for (int off = 1; off < BIN; off <<= 1) {
        int add = (t < BIN && t >= off) ? lrs[t - off] : 0;
        __syncthreads();
        if (t < BIN) lrs[t] += add;
        __syncthreads();
    }
    if (t < BIN) {
        int ex = lrs[t] - ldeg[t];
        cur[t] = ex;
        int n = node0 + t;
        if (n < N) {
            row_start[n] = e0 + ex;
            deg[n] = ldeg[t];
            dinv[n] = rsqrtf((float)(ldeg[t] + 1));
        }
    }
    __syncthreads();
    for (int e = e0 + t; e < e1; e += BS) {
        int2 p = pairs[e];
        int pos = atomicAdd(&cur[p.y - node0], 1);       // LDS atomic
        col[e0 + pos] = p.x;
    }
}

// ---- h1[n][c] = sum_k emb[x[n]][k] * W1[k][c]   (N x 16 @ 16 x 32) ----------
__global__ void k_mm1(const int* __restrict__ x, const float* __restrict__ emb,
                      const float* __restrict__ W1, int N, float* __restrict__ h1) {
    __shared__ float sW[16 * 32];
    __shared__ float sE[8][17];
    int t = threadIdx.x;
    sW[t] = W1[t];
    sW[t + 256] = W1[t + 256];
    int n0 = blockIdx.x * 8;
    if (t < 128) {
        int nl = t >> 4, k = t & 15;
        int n = n0 + nl;
        sE[nl][k] = (n < N) ? emb[x[n] * 16 + k] : 0.f;
    }
    __syncthreads();
    int nl = t >> 5, c = t & 31;
    int n = n0 + nl;
    if (n < N) {
        float acc = 0.f;
        #pragma unroll
        for (int k = 0; k < 16; k++) acc += sE[nl][k] * sW[k * 32 + c];
        h1[n * 32 + c] = acc;
    }
}

// ---- fused layer-1 aggregate + b1 + relu + GEMM W2 -> h2 --------------------
// one WAVE per node: lanes = (edge-half e2) x (channel c in [0,32)).
// 4 independent h1-line gathers in flight per wave; no block barriers in hot path.
__global__ __launch_bounds__(BS) void k_agg1mm2(
    const float* __restrict__ h1, const int* __restrict__ row_start,
    const int* __restrict__ deg, const float* __restrict__ dinv,
    const int* __restrict__ col, const float* __restrict__ b1,
    const float* __restrict__ W2, int N, float* __restrict__ h2) {
    __shared__ float sW[32 * 16];
    int t = threadIdx.x;
    sW[t] = W2[t];
    sW[t + 256] = W2[t + 256];
    __syncthreads();
    int lane = t & 63;
    int n = blockIdx.x * (BS / 64) + (t >> 6);
    if (n >= N) return;
    int e2 = lane >> 5;              // 0 or 1
    int c  = lane & 31;
    int rs = row_start[n];
    int dn = deg[n];
    float acc = 0.f;
    int e = 0;
    for (; e + 4 <= dn; e += 4) {    // 2 gathers/lane in flight
        int s0 = col[rs + e + e2];
        int s1 = col[rs + e + 2 + e2];
        float d0 = dinv[s0];
        float d1 = dinv[s1];
        float v0 = h1[s0 * 32 + c];
        float v1 = h1[s1 * 32 + c];
        acc += d0 * v0 + d1 * v1;
    }
    for (; e + 2 <= dn; e += 2) {
        int s0 = col[rs + e + e2];
        acc += dinv[s0] * h1[s0 * 32 + c];
    }
    if (e + e2 < dn) {
        int s0 = col[rs + e + e2];
        acc += dinv[s0] * h1[s0 * 32 + c];
    }
    acc += __shfl_xor(acc, 32);      // combine edge halves; both halves now hold sum
    float di = dinv[n];
    float h = acc + di * h1[n * 32 + c];            // self-loop
    h = fmaxf(h * di + b1[c], 0.f);                 // norm + bias + relu
    // in-wave GEMM with W2: out[co] = sum_k h(k) * W2[k][co]
    float a = 0.f;
    #pragma unroll
    for (int k = 0; k < 32; k++) {
        float hk = __shfl(h, k);                    // broadcast channel k
        a += hk * sW[k * 16 + (lane & 15)];
    }
    if (lane < 16) h2[n * 16 + lane] = a;
}

// ---- layer-2 aggregate + b2 -> out ------------------------------------------
// one WAVE per node: lanes = (edge-group e4 in [0,4)) x (channel c in [0,16)).
// up to 8 independent h2-line gathers in flight per wave.
__global__ __launch_bounds__(BS) void k_agg2(
    const float* __restrict__ h2, const int* __restrict__ row_start,
    const int* __restrict__ deg, const float* __restrict__ dinv,
    const int* __restrict__ col, const float* __restrict__ b2,
    int N, float* __restrict__ out) {
    int t = threadIdx.x;
    int lane = t & 63;
    int n = blockIdx.x * (BS / 64) + (t >> 6);
    if (n >= N) return;
    int e4 = lane >> 4;              // 0..3
    int c  = lane & 15;
    int rs = row_start[n];
    int dn = deg[n];
    float acc = 0.f;
    int e = 0;
    for (; e + 8 <= dn; e += 8) {    // 2 gathers/lane in flight
        int s0 = col[rs + e + e4];
        int s1 = col[rs + e + 4 + e4];
        float d0 = dinv[s0];
        float d1 = dinv[s1];
        float v0 = h2[s0 * 16 + c];
        float v1 = h2[s1 * 16 + c];
        acc += d0 * v0 + d1 * v1;
    }
    for (; e + 4 <= dn; e += 4) {
        int s0 = col[rs + e + e4];
        acc += dinv[s0] * h2[s0 * 16 + c];
    }
    if (e + e4 < dn) {
        int s0 = col[rs + e + e4];
        acc += dinv[s0] * h2[s0 * 16 + c];
    }
    acc += __shfl_xor(acc, 16);      // combine 4 edge groups
    acc += __shfl_xor(acc, 32);
    float di = dinv[n];
    float v = acc + di * h2[n * 16 + c];
    if (lane < 16) out[n * 16 + c] = v * di + b2[c];
}

extern "C" void kernel_launch(void* const* d_in, const int* in_sizes, int n_in,
                              void* d_out, int out_size, void* d_ws, size_t ws_size,
                              hipStream_t stream) {
    const int*   x   = (const int*)d_in[0];
    const int*   ei  = (const int*)d_in[1];
    const float* emb = (const float*)d_in[2];
    const float* W1  = (const float*)d_in[3];
    const float* b1  = (const float*)d_in[4];
    const float* W2  = (const float*)d_in[5];
    const float* b2  = (const float*)d_in[6];
    float* out = (float*)d_out;

    const int N = in_sizes[0];
    const int E = in_sizes[1] / 2;
    const int* srcp = ei;
    const int* dstp = ei + E;
    const int NBINS = (N + BIN - 1) >> BINSHIFT;   // 782 for N=100000
    const int L = NBINS * NBLK;
    const int nB2 = (L + BS - 1) / BS;

    char* w = (char*)d_ws;
    auto carve = [&](size_t bytes) {
        void* p = (void*)w;
        w += (bytes + 255) & ~size_t(255);
        return p;
    };
    int*   histG     = (int*)carve((size_t)L * 4);
    int*   partial   = (int*)carve((size_t)L * 4);
    int*   bsum      = (int*)carve((size_t)nB2 * 4);
    int*   boff      = (int*)carve((size_t)nB2 * 4);
    int*   scanArr   = (int*)carve((size_t)L * 4);
    int*   row_start = (int*)carve((size_t)N * 4);
    int*   deg       = (int*)carve((size_t)N * 4);
    float* dinv      = (float*)carve((size_t)N * 4);
    int*   col       = (int*)carve((size_t)E * 4);
    // pairs (int2, E*8) and h1 (N*32*4) have disjoint lifetimes -> share
    size_t pairsB = (size_t)E * 8, h1B = (size_t)N * 32 * 4;
    void*  shared12  = carve(pairsB > h1B ? pairsB : h1B);
    int2*  pairs     = (int2*)shared12;
    float* h1        = (float*)shared12;
    float* h2        = (float*)carve((size_t)N * 16 * 4);
    (void)ws_size; (void)n_in; (void)out_size;

    int gL = (L + BS - 1) / BS;
    k_hist<<<NBLK, BS, 0, stream>>>(dstp, E, NBINS, histG);
    k_scanA<<<gL, BS, 0, stream>>>(histG, L, partial, bsum);
    k_scanB<<<1, BS, 0, stream>>>(bsum, nB2, boff);
    k_scanC<<<gL, BS, 0, stream>>>(partial, boff, L, scanArr);
    k_binscatter<<<NBLK, BS, 0, stream>>>(srcp, dstp, E, NBINS, scanArr, pairs);
    k_binsort<<<NBINS, BS, 0, stream>>>(pairs, scanArr, NBINS, N, E,
                                        row_start, deg, dinv, col);

    int g8 = (N + 7) / 8;
    int gW = (N * 64 + BS - 1) / BS;   // one wave (64 lanes) per node
    k_mm1<<<g8, BS, 0, stream>>>(x, emb, W1, N, h1);
    k_agg1mm2<<<gW, BS, 0, stream>>>(h1, row_start, deg, dinv, col, b1, W2, N, h2);
    k_agg2<<<gW, BS, 0, stream>>>(h2, row_start, deg, dinv, col, b2, N, out);
}

// Round 5
// 252.834 us; speedup vs baseline: 2.6690x; 1.0809x over previous
//
#include <hip/hip_runtime.h>

// 2-layer GCN: h1 = emb[x] @ W1; agg+b1+relu; @ W2; agg+b2.
// CSR built per-launch via two-level binned counting sort (no global atomics).
// Aggregation: node-per-wave gather. R5: pre-scaled fp16 features
// (sigma = dinv[n]*h[n], halves gather bytes + kills per-edge dinv chain),
// scalar-cache col loads (readfirstlane), 8 rows in flight per wave.

#define BS   256
#define NBLK 256          // blocks for hist/binscatter passes
#define BINSHIFT 7        // 128 nodes per bin
#define BIN  128
#define MAXBINS 1024

// ---- pass A: per-block histograms of dst bins -------------------------------
__global__ void k_hist(const int* __restrict__ dst, int E, int NBINS,
                       int* __restrict__ histG) {
    __shared__ int h[MAXBINS];
    int t = threadIdx.x;
    for (int i = t; i < NBINS; i += BS) h[i] = 0;
    __syncthreads();
    int chunk = (E + NBLK - 1) / NBLK;
    int s = blockIdx.x * chunk;
    int eend = s + chunk; if (eend > E) eend = E;
    for (int e = s + t; e < eend; e += BS) atomicAdd(&h[dst[e] >> BINSHIFT], 1);
    __syncthreads();
    for (int i = t; i < NBINS; i += BS) histG[i * NBLK + blockIdx.x] = h[i];
}

// ---- hierarchical exclusive scan over L = NBINS*NBLK ints -------------------
__global__ void k_scanA(const int* __restrict__ in, int L,
                        int* __restrict__ partial, int* __restrict__ bsum) {
    __shared__ int s[BS];
    int t = threadIdx.x;
    int i = blockIdx.x * BS + t;
    int v = (i < L) ? in[i] : 0;
    s[t] = v;
    __syncthreads();
    for (int off = 1; off < BS; off <<= 1) {
        int add = (t >= off) ? s[t - off] : 0;
        __syncthreads();
        s[t] += add;
        __syncthreads();
    }
    if (i < L) partial[i] = s[t] - v;
    if (t == BS - 1) bsum[blockIdx.x] = s[BS - 1];
}

__global__ void k_scanB(const int* __restrict__ bsum, int nB, int* __restrict__ boff) {
    __shared__ int s[BS];
    int t = threadIdx.x;
    int PER = (nB + BS - 1) / BS;
    int loc[8];
    int base = t * PER;
    int sum = 0;
    for (int j = 0; j < PER && j < 8; j++) {
        int idx = base + j;
        int v = (idx < nB) ? bsum[idx] : 0;
        loc[j] = sum;
        sum += v;
    }
    s[t] = sum;
    __syncthreads();
    for (int off = 1; off < BS; off <<= 1) {
        int add = (t >= off) ? s[t - off] : 0;
        __syncthreads();
        s[t] += add;
        __syncthreads();
    }
    int ex = s[t] - sum;
    for (int j = 0; j < PER && j < 8; j++) {
        int idx = base + j;
        if (idx < nB) boff[idx] = ex + loc[j];
    }
}

__global__ void k_scanC(const int* __restrict__ partial, const int* __restrict__ boff,
                        int L, int* __restrict__ outArr) {
    int i = blockIdx.x * BS + threadIdx.x;
    if (i < L) outArr[i] = partial[i] + boff[i >> 8];
}

// ---- pass C: scatter edges into bin-partitioned order (LDS cursors only) ----
__global__ void k_binscatter(const int* __restrict__ src, const int* __restrict__ dst,
                             int E, int NBINS, const int* __restrict__ scanArr,
                             int2* __restrict__ pairs) {
    __shared__ int cur[MAXBINS];
    int t = threadIdx.x;
    for (int i = t; i < NBINS; i += BS) cur[i] = scanArr[i * NBLK + blockIdx.x];
    __syncthreads();
    int chunk = (E + NBLK - 1) / NBLK;
    int s = blockIdx.x * chunk;
    int eend = s + chunk; if (eend > E) eend = E;
    for (int e = s + t; e < eend; e += BS) {
        int d = dst[e];
        int pos = atomicAdd(&cur[d >> BINSHIFT], 1);     // LDS atomic
        pairs[pos] = make_int2(src[e], d);
    }
}

// ---- pass D: per-bin counting sort -> final CSR + row_start/dinv ------------
__global__ void k_binsort(const int2* __restrict__ pairs, const int* __restrict__ scanArr,
                          int NBINS, int N, int E,
                          int* __restrict__ row_start, float* __restrict__ dinv,
                          int* __restrict__ col) {
    __shared__ int ldeg[BIN];
    __shared__ int lrs[BIN];
    __shared__ int cur[BIN];
    int b = blockIdx.x;
    int t = threadIdx.x;
    int node0 = b << BINSHIFT;
    int e0 = scanArr[b * NBLK];
    int e1 = (b + 1 < NBINS) ? scanArr[(b + 1) * NBLK] : E;
    if (b == 0 && t == 0) row_start[N] = E;              // sentinel
    if (t < BIN) ldeg[t] = 0;
    __syncthreads();
    for (int e = e0 + t; e < e1; e += BS)
        atomicAdd(&ldeg[pairs[e].y - node0], 1);
    __syncthreads();
    if (t < BIN) lrs[t] = ldeg[t];
    __syncthreads();
    for (int off = 1; off < BIN; off <<= 1) {
        int add = (t < BIN && t >= off) ? lrs[t - off] : 0;
        __syncthreads();
        if (t < BIN) lrs[t] += add;
        __syncthreads();
    }
    if (t < BIN) {
        int ex = lrs[t] - ldeg[t];
        cur[t] = ex;
        int n = node0 + t;
        if (n < N) {
            row_start[n] = e0 + ex;
            dinv[n] = rsqrtf((float)(ldeg[t] + 1));
        }
    }
    __syncthreads();
    for (int e = e0 + t; e < e1; e += BS) {
        int2 p = pairs[e];
        int pos = atomicAdd(&cur[p.y - node0], 1);       // LDS atomic
        col[e0 + pos] = p.x;
    }
}

// ---- sig1[n][c] = dinv[n] * sum_k emb[x[n]][k] * W1[k][c]  (fp16 out) -------
__global__ void k_mm1(const int* __restrict__ x, const float* __restrict__ emb,
                      const float* __restrict__ W1, const float* __restrict__ dinv,
                      int N, _Float16* __restrict__ sig1) {
    __shared__ float sW[16 * 32];
    __shared__ float sE[8][17];
    int t = threadIdx.x;
    sW[t] = W1[t];
    sW[t + 256] = W1[t + 256];
    int n0 = blockIdx.x * 8;
    if (t < 128) {
        int nl = t >> 4, k = t & 15;
        int n = n0 + nl;
        sE[nl][k] = (n < N) ? emb[x[n] * 16 + k] : 0.f;
    }
    __syncthreads();
    int nl = t >> 5, c = t & 31;
    int n = n0 + nl;
    if (n < N) {
        float acc = 0.f;
        #pragma unroll
        for (int k = 0; k < 16; k++) acc += sE[nl][k] * sW[k * 32 + c];
        sig1[n * 32 + c] = (_Float16)(acc * dinv[n]);
    }
}

// ---- fused layer-1 aggregate + b1 + relu + GEMM W2 -> sig2 (fp16) -----------
// one WAVE per node; lanes = (edge-half e2) x (channel c in [0,32)).
// scalar col loads; 4 ushort gathers in flight per lane (8 rows per wave).
__global__ __launch_bounds__(BS) void k_agg1mm2(
    const _Float16* __restrict__ sig1, const int* __restrict__ row_start,
    const float* __restrict__ dinv, const int* __restrict__ col,
    const float* __restrict__ b1, const float* __restrict__ W2,
    int N, _Float16* __restrict__ sig2) {
    __shared__ float sW[32 * 16];
    int t = threadIdx.x;
    sW[t] = W2[t];
    sW[t + 256] = W2[t + 256];
    __syncthreads();
    int lane = t & 63;
    int n = blockIdx.x * (BS / 64) + (t >> 6);
    if (n >= N) return;
    int e2 = lane >> 5;              // 0 or 1
    int c  = lane & 31;
    int rs = __builtin_amdgcn_readfirstlane(row_start[n]);
    int re = __builtin_amdgcn_readfirstlane(row_start[n + 1]);
    int dn = re - rs;
    float acc = 0.f;
    int e = 0;
    for (; e + 8 <= dn; e += 8) {
        const int* cu = col + rs + e;            // uniform address -> s_load
        int c0 = cu[0], c1 = cu[1], c2 = cu[2], c3 = cu[3];
        int c4 = cu[4], c5 = cu[5], c6 = cu[6], c7 = cu[7];
        int s0 = e2 ? c1 : c0;
        int s1 = e2 ? c3 : c2;
        int s2 = e2 ? c5 : c4;
        int s3 = e2 ? c7 : c6;
        float v0 = (float)sig1[s0 * 32 + c];
        float v1 = (float)sig1[s1 * 32 + c];
        float v2 = (float)sig1[s2 * 32 + c];
        float v3 = (float)sig1[s3 * 32 + c];
        acc += v0 + v1 + v2 + v3;
    }
    for (; e + 2 <= dn; e += 2) {
        const int* cu = col + rs + e;
        int c0 = cu[0], c1 = cu[1];
        int s0 = e2 ? c1 : c0;
        acc += (float)sig1[s0 * 32 + c];
    }
    if (e + e2 < dn) {
        int s0 = col[rs + e + e2];
        acc += (float)sig1[s0 * 32 + c];
    }
    acc += __shfl_xor(acc, 32);                  // combine edge halves
    acc += (float)sig1[n * 32 + c];              // self-loop (= dinv_n*h1_n)
    float di = dinv[n];
    float h = fmaxf(acc * di + b1[c], 0.f);      // norm + bias + relu
    // in-wave GEMM with W2
    float a = 0.f;
    #pragma unroll
    for (int k = 0; k < 32; k++) {
        float hk = __shfl(h, k);
        a += hk * sW[k * 16 + (lane & 15)];
    }
    if (lane < 16) sig2[n * 16 + lane] = (_Float16)(a * di);   // pre-scale by dinv_n
}

// ---- layer-2 aggregate + b2 -> out ------------------------------------------
// one WAVE per node; lanes = (edge-group e4 in [0,4)) x (channel c in [0,16)).
__global__ __launch_bounds__(BS) void k_agg2(
    const _Float16* __restrict__ sig2, const int* __restrict__ row_start,
    const float* __restrict__ dinv, const int* __restrict__ col,
    const float* __restrict__ b2, int N, float* __restrict__ out) {
    int t = threadIdx.x;
    int lane = t & 63;
    int n = blockIdx.x * (BS / 64) + (t >> 6);
    if (n >= N) return;
    int e4 = lane >> 4;              // 0..3
    int c  = lane & 15;
    int rs = __builtin_amdgcn_readfirstlane(row_start[n]);
    int re = __builtin_amdgcn_readfirstlane(row_start[n + 1]);
    int dn = re - rs;
    float acc = 0.f;
    int e = 0;
    for (; e + 8 <= dn; e += 8) {
        const int* cu = col + rs + e;
        int c0 = cu[0], c1 = cu[1], c2 = cu[2], c3 = cu[3];
        int c4 = cu[4], c5 = cu[5], c6 = cu[6], c7 = cu[7];
        int sA = (e4 & 1) ? c1 : c0;
        int sB = (e4 & 1) ? c3 : c2;
        int s0 = (e4 & 2) ? sB : sA;
        int sC = (e4 & 1) ? c5 : c4;
        int sD = (e4 & 1) ? c7 : c6;
        int s1 = (e4 & 2) ? sD : sC;
        float v0 = (float)sig2[s0 * 16 + c];
        float v1 = (float)sig2[s1 * 16 + c];
        acc += v0 + v1;
    }
    for (; e + 4 <= dn; e += 4) {
        const int* cu = col + rs + e;
        int c0 = cu[0], c1 = cu[1], c2 = cu[2], c3 = cu[3];
        int sA = (e4 & 1) ? c1 : c0;
        int sB = (e4 & 1) ? c3 : c2;
        int s0 = (e4 & 2) ? sB : sA;
        acc += (float)sig2[s0 * 16 + c];
    }
    if (e + e4 < dn) {
        int s0 = col[rs + e + e4];
        acc += (float)sig2[s0 * 16 + c];
    }
    acc += __shfl_xor(acc, 16);      // combine 4 edge groups
    acc += __shfl_xor(acc, 32);
    acc += (float)sig2[n * 16 + c];  // self-loop
    if (lane < 16) out[n * 16 + c] = acc * dinv[n] + b2[c];
}

extern "C" void kernel_launch(void* const* d_in, const int* in_sizes, int n_in,
                              void* d_out, int out_size, void* d_ws, size_t ws_size,
                              hipStream_t stream) {
    const int*   x   = (const int*)d_in[0];
    const int*   ei  = (const int*)d_in[1];
    const float* emb = (const float*)d_in[2];
    const float* W1  = (const float*)d_in[3];
    const float* b1  = (const float*)d_in[4];
    const float* W2  = (const float*)d_in[5];
    const float* b2  = (const float*)d_in[6];
    float* out = (float*)d_out;

    const int N = in_sizes[0];
    const int E = in_sizes[1] / 2;
    const int* srcp = ei;
    const int* dstp = ei + E;
    const int NBINS = (N + BIN - 1) >> BINSHIFT;   // 782 for N=100000
    const int L = NBINS * NBLK;
    const int nB2 = (L + BS - 1) / BS;

    char* w = (char*)d_ws;
    auto carve = [&](size_t bytes) {
        void* p = (void*)w;
        w += (bytes + 255) & ~size_t(255);
        return p;
    };
    int*   histG     = (int*)carve((size_t)L * 4);
    int*   partial   = (int*)carve((size_t)L * 4);
    int*   bsum      = (int*)carve((size_t)nB2 * 4);
    int*   boff      = (int*)carve((size_t)nB2 * 4);
    int*   scanArr   = (int*)carve((size_t)L * 4);
    int*   row_start = (int*)carve((size_t)(N + 1) * 4);
    float* dinv      = (float*)carve((size_t)N * 4);
    int*   col       = (int*)carve((size_t)E * 4);
    // pairs (int2, E*8) and sig1/sig2 (N*32*2 + N*16*2) have disjoint
    // lifetimes -> share one region
    size_t sig1B = ((size_t)N * 32 * 2 + 255) & ~size_t(255);
    size_t sigB  = sig1B + (size_t)N * 16 * 2;
    size_t pairsB = (size_t)E * 8;
    void*  shared12  = carve(pairsB > sigB ? pairsB : sigB);
    int2*      pairs = (int2*)shared12;
    _Float16*  sig1  = (_Float16*)shared12;
    _Float16*  sig2  = (_Float16*)((char*)shared12 + sig1B);
    (void)ws_size; (void)n_in; (void)out_size;

    int gL = (L + BS - 1) / BS;
    k_hist<<<NBLK, BS, 0, stream>>>(dstp, E, NBINS, histG);
    k_scanA<<<gL, BS, 0, stream>>>(histG, L, partial, bsum);
    k_scanB<<<1, BS, 0, stream>>>(bsum, nB2, boff);
    k_scanC<<<gL, BS, 0, stream>>>(partial, boff, L, scanArr);
    k_binscatter<<<NBLK, BS, 0, stream>>>(srcp, dstp, E, NBINS, scanArr, pairs);
    k_binsort<<<NBINS, BS, 0, stream>>>(pairs, scanArr, NBINS, N, E,
                                        row_start, dinv, col);

    int g8 = (N + 7) / 8;
    int gW = (N * 64 + BS - 1) / BS;   // one wave (64 lanes) per node
    k_mm1<<<g8, BS, 0, stream>>>(x, emb, W1, dinv, N, sig1);
    k_agg1mm2<<<gW, BS, 0, stream>>>(sig1, row_start, dinv, col, b1, W2, N, sig2);
    k_agg2<<<gW, BS, 0, stream>>>(sig2, row_start, dinv, col, b2, N, out);
}

// Round 6
// 229.630 us; speedup vs baseline: 2.9387x; 1.1010x over previous
//
#include <hip/hip_runtime.h>

// 2-layer GCN: h1 = emb[x] @ W1; agg+b1+relu; @ W2; agg+b2.
// CSR built per-launch via two-level binned counting sort (no global atomics).
// Aggregation: node-per-wave gather, pre-scaled fp16 features, scalar col
// loads. R6: 16-edge unroll (8 gathers in flight/lane), geometric tails,
// split-half W2 shuffle-GEMM (17 vs 32 cross-lane ops), scanC folded away.

#define BS   256
#define NBLK 256          // blocks for hist/binscatter passes (MUST stay 256: idx>>8==bin)
#define BINSHIFT 7        // 128 nodes per bin
#define BIN  128
#define MAXBINS 1024

// ---- pass A: per-block histograms of dst bins -------------------------------
__global__ void k_hist(const int* __restrict__ dst, int E, int NBINS,
                       int* __restrict__ histG) {
    __shared__ int h[MAXBINS];
    int t = threadIdx.x;
    for (int i = t; i < NBINS; i += BS) h[i] = 0;
    __syncthreads();
    int chunk = (E + NBLK - 1) / NBLK;
    int s = blockIdx.x * chunk;
    int eend = s + chunk; if (eend > E) eend = E;
    for (int e = s + t; e < eend; e += BS) atomicAdd(&h[dst[e] >> BINSHIFT], 1);
    __syncthreads();
    for (int i = t; i < NBINS; i += BS) histG[i * NBLK + blockIdx.x] = h[i];
}

// ---- hierarchical exclusive scan over L = NBINS*NBLK ints -------------------
__global__ void k_scanA(const int* __restrict__ in, int L,
                        int* __restrict__ partial, int* __restrict__ bsum) {
    __shared__ int s[BS];
    int t = threadIdx.x;
    int i = blockIdx.x * BS + t;
    int v = (i < L) ? in[i] : 0;
    s[t] = v;
    __syncthreads();
    for (int off = 1; off < BS; off <<= 1) {
        int add = (t >= off) ? s[t - off] : 0;
        __syncthreads();
        s[t] += add;
        __syncthreads();
    }
    if (i < L) partial[i] = s[t] - v;
    if (t == BS - 1) bsum[blockIdx.x] = s[BS - 1];
}

__global__ void k_scanB(const int* __restrict__ bsum, int nB, int* __restrict__ boff) {
    __shared__ int s[BS];
    int t = threadIdx.x;
    int PER = (nB + BS - 1) / BS;
    int loc[8];
    int base = t * PER;
    int sum = 0;
    for (int j = 0; j < PER && j < 8; j++) {
        int idx = base + j;
        int v = (idx < nB) ? bsum[idx] : 0;
        loc[j] = sum;
        sum += v;
    }
    s[t] = sum;
    __syncthreads();
    for (int off = 1; off < BS; off <<= 1) {
        int add = (t >= off) ? s[t - off] : 0;
        __syncthreads();
        s[t] += add;
        __syncthreads();
    }
    int ex = s[t] - sum;
    for (int j = 0; j < PER && j < 8; j++) {
        int idx = base + j;
        if (idx < nB) boff[idx] = ex + loc[j];
    }
}

// ---- pass C: scatter edges into bin-partitioned order (LDS cursors only) ----
// offset for (bin i, block blk) = partial[i*NBLK+blk] + boff[i]  (NBLK==256)
__global__ void k_binscatter(const int* __restrict__ src, const int* __restrict__ dst,
                             int E, int NBINS, const int* __restrict__ partial,
                             const int* __restrict__ boff, int2* __restrict__ pairs) {
    __shared__ int cur[MAXBINS];
    int t = threadIdx.x;
    for (int i = t; i < NBINS; i += BS)
        cur[i] = partial[i * NBLK + blockIdx.x] + boff[i];
    __syncthreads();
    int chunk = (E + NBLK - 1) / NBLK;
    int s = blockIdx.x * chunk;
    int eend = s + chunk; if (eend > E) eend = E;
    for (int e = s + t; e < eend; e += BS) {
        int d = dst[e];
        int pos = atomicAdd(&cur[d >> BINSHIFT], 1);     // LDS atomic
        pairs[pos] = make_int2(src[e], d);
    }
}

// ---- pass D: per-bin counting sort -> final CSR + row_start/dinv ------------
__global__ void k_binsort(const int2* __restrict__ pairs, const int* __restrict__ partial,
                          const int* __restrict__ boff, int NBINS, int N, int E,
                          int* __restrict__ row_start, float* __restrict__ dinv,
                          int* __restrict__ col) {
    __shared__ int ldeg[BIN];
    __shared__ int lrs[BIN];
    __shared__ int cur[BIN];
    int b = blockIdx.x;
    int t = threadIdx.x;
    int node0 = b << BINSHIFT;
    int e0 = partial[b * NBLK] + boff[b];
    int e1 = (b + 1 < NBINS) ? (partial[(b + 1) * NBLK] + boff[b + 1]) : E;
    if (b == 0 && t == 0) row_start[N] = E;              // sentinel
    if (t < BIN) ldeg[t] = 0;
    __syncthreads();
    for (int e = e0 + t; e < e1; e += BS)
        atomicAdd(&ldeg[pairs[e].y - node0], 1);
    __syncthreads();
    if (t < BIN) lrs[t] = ldeg[t];
    __syncthreads();
    for (int off = 1; off < BIN; off <<= 1) {
        int add = (t < BIN && t >= off) ? lrs[t - off] : 0;
        __syncthreads();
        if (t < BIN) lrs[t] += add;
        __syncthreads();
    }
    if (t < BIN) {
        int ex = lrs[t] - ldeg[t];
        cur[t] = ex;
        int n = node0 + t;
        if (n < N) {
            row_start[n] = e0 + ex;
            dinv[n] = rsqrtf((float)(ldeg[t] + 1));
        }
    }
    __syncthreads();
    for (int e = e0 + t; e < e1; e += BS) {
        int2 p = pairs[e];
        int pos = atomicAdd(&cur[p.y - node0], 1);       // LDS atomic
        col[e0 + pos] = p.x;
    }
}

// ---- sig1[n][c] = dinv[n] * sum_k emb[x[n]][k] * W1[k][c]  (fp16 out) -------
__global__ void k_mm1(const int* __restrict__ x, const float* __restrict__ emb,
                      const float* __restrict__ W1, const float* __restrict__ dinv,
                      int N, _Float16* __restrict__ sig1) {
    __shared__ float sW[16 * 32];
    __shared__ float sE[8][17];
    int t = threadIdx.x;
    sW[t] = W1[t];
    sW[t + 256] = W1[t + 256];
    int n0 = blockIdx.x * 8;
    if (t < 128) {
        int nl = t >> 4, k = t & 15;
        int n = n0 + nl;
        sE[nl][k] = (n < N) ? emb[x[n] * 16 + k] : 0.f;
    }
    __syncthreads();
    int nl = t >> 5, c = t & 31;
    int n = n0 + nl;
    if (n < N) {
        float acc = 0.f;
        #pragma unroll
        for (int k = 0; k < 16; k++) acc += sE[nl][k] * sW[k * 32 + c];
        sig1[n * 32 + c] = (_Float16)(acc * dinv[n]);
    }
}

// ---- fused layer-1 aggregate + b1 + relu + GEMM W2 -> sig2 (fp16) -----------
// one WAVE per node; lanes = (edge-half e2) x (channel c in [0,32)).
// 16-edge unroll: 8 ushort gathers in flight per lane; geometric tails.
__global__ __launch_bounds__(BS) void k_agg1mm2(
    const _Float16* __restrict__ sig1, const int* __restrict__ row_start,
    const float* __restrict__ dinv, const int* __restrict__ col,
    const float* __restrict__ b1, const float* __restrict__ W2,
    int N, _Float16* __restrict__ sig2) {
    __shared__ float sW[32 * 16];
    int t = threadIdx.x;
    sW[t] = W2[t];
    sW[t + 256] = W2[t + 256];
    __syncthreads();
    int lane = t & 63;
    int n = blockIdx.x * (BS / 64) + (t >> 6);
    if (n >= N) return;
    int e2 = lane >> 5;              // 0 or 1
    int c  = lane & 31;
    int rs = __builtin_amdgcn_readfirstlane(row_start[n]);
    int re = __builtin_amdgcn_readfirstlane(row_start[n + 1]);
    int dn = re - rs;
    float acc = 0.f;
    int e = 0;
    for (; e + 16 <= dn; e += 16) {
        const int* cu = col + rs + e;            // uniform -> s_load
        int s0 = e2 ? cu[1]  : cu[0];
        int s1 = e2 ? cu[3]  : cu[2];
        int s2 = e2 ? cu[5]  : cu[4];
        int s3 = e2 ? cu[7]  : cu[6];
        int s4 = e2 ? cu[9]  : cu[8];
        int s5 = e2 ? cu[11] : cu[10];
        int s6 = e2 ? cu[13] : cu[12];
        int s7 = e2 ? cu[15] : cu[14];
        float v0 = (float)sig1[s0 * 32 + c];
        float v1 = (float)sig1[s1 * 32 + c];
        float v2 = (float)sig1[s2 * 32 + c];
        float v3 = (float)sig1[s3 * 32 + c];
        float v4 = (float)sig1[s4 * 32 + c];
        float v5 = (float)sig1[s5 * 32 + c];
        float v6 = (float)sig1[s6 * 32 + c];
        float v7 = (float)sig1[s7 * 32 + c];
        acc += ((v0 + v1) + (v2 + v3)) + ((v4 + v5) + (v6 + v7));
    }
    if (e + 8 <= dn) {
        const int* cu = col + rs + e;
        int s0 = e2 ? cu[1] : cu[0];
        int s1 = e2 ? cu[3] : cu[2];
        int s2 = e2 ? cu[5] : cu[4];
        int s3 = e2 ? cu[7] : cu[6];
        float v0 = (float)sig1[s0 * 32 + c];
        float v1 = (float)sig1[s1 * 32 + c];
        float v2 = (float)sig1[s2 * 32 + c];
        float v3 = (float)sig1[s3 * 32 + c];
        acc += (v0 + v1) + (v2 + v3);
        e += 8;
    }
    if (e + 4 <= dn) {
        const int* cu = col + rs + e;
        int s0 = e2 ? cu[1] : cu[0];
        int s1 = e2 ? cu[3] : cu[2];
        acc += (float)sig1[s0 * 32 + c] + (float)sig1[s1 * 32 + c];
        e += 4;
    }
    if (e + 2 <= dn) {
        const int* cu = col + rs + e;
        int s0 = e2 ? cu[1] : cu[0];
        acc += (float)sig1[s0 * 32 + c];
        e += 2;
    }
    if (e + e2 < dn) {
        int s0 = col[rs + e + e2];
        acc += (float)sig1[s0 * 32 + c];
    }
    acc += __shfl_xor(acc, 32);                  // combine edge halves
    acc += (float)sig1[n * 32 + c];              // self-loop (= dinv_n*h1_n)
    float di = dinv[n];
    float h = fmaxf(acc * di + b1[c], 0.f);      // norm + bias + relu
    // split-half W2 GEMM: half0 sums k=0..15 (from lanes 0..15),
    // half1 sums k=16..31 (from lanes 48..63); combine via shfl_xor(32).
    int half = lane >> 5;
    int co = lane & 15;
    int srcBase = half * 48;                     // half0: lanes 0+k; half1: 48+k
    const float* wrow = sW + (half * 16) * 16 + co;
    float a = 0.f;
    #pragma unroll
    for (int k = 0; k < 16; k++) {
        float hk = __shfl(h, srcBase + k);
        a += hk * wrow[k * 16];
    }
    a += __shfl_xor(a, 32);
    if (lane < 16) sig2[n * 16 + lane] = (_Float16)(a * di);   // pre-scale by dinv_n
}

// ---- layer-2 aggregate + b2 -> out ------------------------------------------
// one WAVE per node; lanes = (edge-group e4 in [0,4)) x (channel c in [0,16)).
// 16-edge unroll: 4 gathers in flight per lane.
__global__ __launch_bounds__(BS) void k_agg2(
    const _Float16* __restrict__ sig2, const int* __restrict__ row_start,
    const float* __restrict__ dinv, const int* __restrict__ col,
    const float* __restrict__ b2, int N, float* __restrict__ out) {
    int t = threadIdx.x;
    int lane = t & 63;
    int n = blockIdx.x * (BS / 64) + (t >> 6);
    if (n >= N) return;
    int e4 = lane >> 4;              // 0..3
    int c  = lane & 15;
    int rs = __builtin_amdgcn_readfirstlane(row_start[n]);
    int re = __builtin_amdgcn_readfirstlane(row_start[n + 1]);
    int dn = re - rs;
    float acc = 0.f;
    int e = 0;
    for (; e + 16 <= dn; e += 16) {
        const int* cu = col + rs + e;
        int sA0 = (e4 & 1) ? cu[1]  : cu[0];
        int sB0 = (e4 & 1) ? cu[3]  : cu[2];
        int s0  = (e4 & 2) ? sB0 : sA0;
        int sA1 = (e4 & 1) ? cu[5]  : cu[4];
        int sB1 = (e4 & 1) ? cu[7]  : cu[6];
        int s1  = (e4 & 2) ? sB1 : sA1;
        int sA2 = (e4 & 1) ? cu[9]  : cu[8];
        int sB2 = (e4 & 1) ? cu[11] : cu[10];
        int s2  = (e4 & 2) ? sB2 : sA2;
        int sA3 = (e4 & 1) ? cu[13] : cu[12];
        int sB3 = (e4 & 1) ? cu[15] : cu[14];
        int s3  = (e4 & 2) ? sB3 : sA3;
        float v0 = (float)sig2[s0 * 16 + c];
        float v1 = (float)sig2[s1 * 16 + c];
        float v2 = (float)sig2[s2 * 16 + c];
        float v3 = (float)sig2[s3 * 16 + c];
        acc += (v0 + v1) + (v2 + v3);
    }
    if (e + 8 <= dn) {
        const int* cu = col + rs + e;
        int sA0 = (e4 & 1) ? cu[1] : cu[0];
        int sB0 = (e4 & 1) ? cu[3] : cu[2];
        int s0  = (e4 & 2) ? sB0 : sA0;
        int sA1 = (e4 & 1) ? cu[5] : cu[4];
        int sB1 = (e4 & 1) ? cu[7] : cu[6];
        int s1  = (e4 & 2) ? sB1 : sA1;
        acc += (float)sig2[s0 * 16 + c] + (float)sig2[s1 * 16 + c];
        e += 8;
    }
    if (e + 4 <= dn) {
        const int* cu = col + rs + e;
        int sA = (e4 & 1) ? cu[1] : cu[0];
        int sB = (e4 & 1) ? cu[3] : cu[2];
        int s0 = (e4 & 2) ? sB : sA;
        acc += (float)sig2[s0 * 16 + c];
        e += 4;
    }
    {
        int rem = dn - e;
        if (e4 < rem) {
            int s0 = col[rs + e + e4];
            acc += (float)sig2[s0 * 16 + c];
        }
    }
    acc += __shfl_xor(acc, 16);      // combine 4 edge groups
    acc += __shfl_xor(acc, 32);
    acc += (float)sig2[n * 16 + c];  // self-loop
    if (lane < 16) out[n * 16 + c] = acc * dinv[n] + b2[c];
}

extern "C" void kernel_launch(void* const* d_in, const int* in_sizes, int n_in,
                              void* d_out, int out_size, void* d_ws, size_t ws_size,
                              hipStream_t stream) {
    const int*   x   = (const int*)d_in[0];
    const int*   ei  = (const int*)d_in[1];
    const float* emb = (const float*)d_in[2];
    const float* W1  = (const float*)d_in[3];
    const float* b1  = (const float*)d_in[4];
    const float* W2  = (const float*)d_in[5];
    const float* b2  = (const float*)d_in[6];
    float* out = (float*)d_out;

    const int N = in_sizes[0];
    const int E = in_sizes[1] / 2;
    const int* srcp = ei;
    const int* dstp = ei + E;
    const int NBINS = (N + BIN - 1) >> BINSHIFT;   // 782 for N=100000
    const int L = NBINS * NBLK;
    const int nB2 = (L + BS - 1) / BS;             // == NBINS (NBLK==BS==256)

    char* w = (char*)d_ws;
    auto carve = [&](size_t bytes) {
        void* p = (void*)w;
        w += (bytes + 255) & ~size_t(255);
        return p;
    };
    int*   histG     = (int*)carve((size_t)L * 4);
    int*   partial   = (int*)carve((size_t)L * 4);
    int*   bsum      = (int*)carve((size_t)nB2 * 4);
    int*   boff      = (int*)carve((size_t)nB2 * 4);
    int*   row_start = (int*)carve((size_t)(N + 1) * 4);
    float* dinv      = (float*)carve((size_t)N * 4);
    int*   col       = (int*)carve((size_t)E * 4);
    // pairs (int2, E*8) and sig1/sig2 have disjoint lifetimes -> share
    size_t sig1B = ((size_t)N * 32 * 2 + 255) & ~size_t(255);
    size_t sigB  = sig1B + (size_t)N * 16 * 2;
    size_t pairsB = (size_t)E * 8;
    void*  shared12  = carve(pairsB > sigB ? pairsB : sigB);
    int2*      pairs = (int2*)shared12;
    _Float16*  sig1  = (_Float16*)shared12;
    _Float16*  sig2  = (_Float16*)((char*)shared12 + sig1B);
    (void)ws_size; (void)n_in; (void)out_size;

    int gL = (L + BS - 1) / BS;
    k_hist<<<NBLK, BS, 0, stream>>>(dstp, E, NBINS, histG);
    k_scanA<<<gL, BS, 0, stream>>>(histG, L, partial, bsum);
    k_scanB<<<1, BS, 0, stream>>>(bsum, nB2, boff);
    k_binscatter<<<NBLK, BS, 0, stream>>>(srcp, dstp, E, NBINS, partial, boff, pairs);
    k_binsort<<<NBINS, BS, 0, stream>>>(pairs, partial, boff, NBINS, N, E,
                                        row_start, dinv, col);

    int g8 = (N + 7) / 8;
    int gW = (N * 64 + BS - 1) / BS;   // one wave (64 lanes) per node
    k_mm1<<<g8, BS, 0, stream>>>(x, emb, W1, dinv, N, sig1);
    k_agg1mm2<<<gW, BS, 0, stream>>>(sig1, row_start, dinv, col, b1, W2, N, sig2);
    k_agg2<<<gW, BS, 0, stream>>>(sig2, row_start, dinv, col, b2, N, out);
}